// Round 4
// baseline (419.794 us; speedup 1.0000x reference)
//
#include <hip/hip_runtime.h>
#include <cstdint>

// ---------------------------------------------------------------------------
// Attention (Luong general): out = softmax(dec @ (enc@W)^T) @ enc
// B=8, S_enc=S_dec=2048, H=512, fp32 in/out.
//
// bf16 MFMA; split-precision (hi+lo bf16, 3-term) for the matmuls feeding
// softmax (logit std ~512, top-2 gap ~131: plain bf16 would flip argmaxes).
// Round 4 (= round 3 with compile fix): softmax fused away --
//   * logits gemm epilogue emits per-(row, n-tile) online-softmax partials
//   * tiny combine kernel -> per-row (max, 1/sum)
//   * PV kernel stages A = exp(S - m) -> bf16 through registers (dbuf'd),
//     scales by 1/l in the epilogue.  P never materialized.
// Fix vs r3: no LDS pointer arrays (addrspacecast-in-initializer rejected);
// use offset arithmetic off one extern __shared__ base instead.
// ---------------------------------------------------------------------------

#define DEVINL __device__ __forceinline__

typedef __attribute__((ext_vector_type(8))) short short8;
typedef __attribute__((ext_vector_type(4))) float f32x4;

DEVINL short f2bf(float x) {
    union { float f; uint32_t u; } v; v.f = x;
    uint32_t r = v.u + 0x7FFFu + ((v.u >> 16) & 1u);   // RNE
    return (short)(r >> 16);
}
DEVINL float bf2f(short h) {
    union { uint32_t u; float f; } v; v.u = ((uint32_t)(uint16_t)h) << 16;
    return v.f;
}

DEVINL void gload_lds16(const void* g, void* l) {
    __builtin_amdgcn_global_load_lds(
        (const __attribute__((address_space(1))) char*)g,
        (__attribute__((address_space(3))) char*)l, 16, 0, 0);
}

// ---------------------------------------------------------------------------
// split fp32 -> (hi, lo) bf16 arrays.  8 elems/thread, exact-cover grids.
// ---------------------------------------------------------------------------
__global__ __launch_bounds__(256)
void split_kernel(const float* __restrict__ x, short* __restrict__ hi,
                  short* __restrict__ lo)
{
    long i = ((long)blockIdx.x * 256 + threadIdx.x) * 8;
    f32x4 a = *(const f32x4*)(x + i);
    f32x4 b = *(const f32x4*)(x + i + 4);
    short8 h, l;
#pragma unroll
    for (int j = 0; j < 4; j++) {
        short ha = f2bf(a[j]); h[j] = ha;     l[j] = f2bf(a[j] - bf2f(ha));
        short hb = f2bf(b[j]); h[4 + j] = hb; l[4 + j] = f2bf(b[j] - bf2f(hb));
    }
    *(short8*)(hi + i) = h;
    *(short8*)(lo + i) = l;
}

// W[512k][512n] -> Wt_hi/lo[n][k]
__global__ __launch_bounds__(256)
void split_w_kernel(const float* __restrict__ w, short* __restrict__ wth,
                    short* __restrict__ wtl)
{
    int idx = blockIdx.x * 256 + threadIdx.x;   // k*512 + n
    int k = idx >> 9, n = idx & 511;
    float v = w[idx];
    short h = f2bf(v);
    wth[(long)n * 512 + k] = h;
    wtl[(long)n * 512 + k] = f2bf(v - bf2f(h));
}

// enc_hi[b][s][e] bf16 -> enc_t[b][e][s] bf16 (PV B-operand)
__global__ __launch_bounds__(256)
void transpose_bf16_kernel(const short* __restrict__ x, short* __restrict__ xt)
{
    __shared__ short tile[32][33];
    const int b  = blockIdx.z;
    const int s0 = blockIdx.x * 32;
    const int e0 = blockIdx.y * 32;
    const short* px = x + (long)b * 2048 * 512;
    short* pt = xt + (long)b * 512 * 2048;
    const int tx = threadIdx.x & 31;
    const int ty = threadIdx.x >> 5;   // 0..7
#pragma unroll
    for (int r = 0; r < 32; r += 8)
        tile[ty + r][tx] = px[(long)(s0 + ty + r) * 512 + e0 + tx];
    __syncthreads();
#pragma unroll
    for (int r = 0; r < 32; r += 8)
        pt[(long)(e0 + ty + r) * 2048 + s0 + tx] = tile[tx][ty + r];
}

// ---------------------------------------------------------------------------
// gemm_bt: C[m][n] = sum_k A[m][k]*B[n][k]  (both operands K-contiguous).
// 128x128 tile, BK=32, 4 waves (2x2 of 64x64), 16x16x32 bf16 MFMA,
// double-buffered LDS staging (one barrier/iter; prefetch before consume).
// NTERMS=3: acc += Ah*Bh + Ah*Bl + Al*Bh.
// SPLIT_OUT: write hi/lo bf16 pair (for enc_proj).
// STATS: epilogue also writes per-(row, n-tile) softmax partials
//   stats[(b*2048+row)*16 + blockIdx.x] = (m_p, sum_j exp(x - m_p)).
// ---------------------------------------------------------------------------
template<int NTERMS, bool SPLIT_OUT, bool STATS>
__global__ __launch_bounds__(256, 2)
void gemm_bt(const short* __restrict__ Ah, const short* __restrict__ Al,
             const short* __restrict__ Bh, const short* __restrict__ Bl,
             float* __restrict__ C, short* __restrict__ Ch, short* __restrict__ Cl,
             float2* __restrict__ stats,
             int K, int lda, int ldb, int ldc,
             long sA, long sB, long sC)
{
    extern __shared__ char smem_raw[];
    constexpr int OPS = (NTERMS == 3) ? 4 : 2;     // operand planes per set
    constexpr int SET = 128 * 32 * OPS;            // shorts per buffer set
    short* smem = (short*)smem_raw;                // 2 sets (+1KB stats)

    const int tid  = threadIdx.x;
    const int wave = tid >> 6;
    const int lane = tid & 63;
    const int quad = lane >> 4;
    const int l16  = lane & 15;
    const int wm   = (wave >> 1) * 64;
    const int wn   = (wave & 1) * 64;

    const long tile_m = (long)blockIdx.y * 128;
    const long tile_n = (long)blockIdx.x * 128;
    const int  bz     = blockIdx.z;

    const short* pAh = Ah + (long)bz * sA;
    const short* pBh = Bh + (long)bz * sB;
    const short* pAl = (NTERMS == 3) ? (Al + (long)bz * sA) : nullptr;
    const short* pBl = (NTERMS == 3) ? (Bl + (long)bz * sB) : nullptr;

    // staging: thread t -> row t>>2, k-subchunk (t&3)*8; LDS byte off = 16*t
    const int srow = tid >> 2;
    const int skq  = (tid & 3) * 8;
    const int lds_off = srow * 32 + skq;
    const long ga0 = (tile_m + srow) * (long)lda + skq;
    const long gb0 = (tile_n + srow) * (long)ldb + skq;

    auto stage = [&](int k0, int buf) {
        short* s   = smem + buf * SET;
        short* ash = s;
        short* bsh = s + 128 * 32;
        gload_lds16(pAh + ga0 + k0,             ash + lds_off);
        gload_lds16(pAh + ga0 + 64l * lda + k0, ash + lds_off + 64 * 32);
        gload_lds16(pBh + gb0 + k0,             bsh + lds_off);
        gload_lds16(pBh + gb0 + 64l * ldb + k0, bsh + lds_off + 64 * 32);
        if constexpr (NTERMS == 3) {
            short* asl = s + 2 * 128 * 32;
            short* bsl = s + 3 * 128 * 32;
            gload_lds16(pAl + ga0 + k0,             asl + lds_off);
            gload_lds16(pAl + ga0 + 64l * lda + k0, asl + lds_off + 64 * 32);
            gload_lds16(pBl + gb0 + k0,             bsl + lds_off);
            gload_lds16(pBl + gb0 + 64l * ldb + k0, bsl + lds_off + 64 * 32);
        }
    };

    f32x4 acc[4][4] = {};
    stage(0, 0);
    int cur = 0;

    for (int k0 = 0; k0 < K; k0 += 32) {
        __syncthreads();                    // drains vmcnt: stage(cur) done
        if (k0 + 32 < K) stage(k0 + 32, cur ^ 1);   // prefetch next tile

        short* s   = smem + cur * SET;
        short* ash = s;
        short* bsh = s + 128 * 32;
        short* asl = s + 2 * 128 * 32;
        short* bsl = s + 3 * 128 * 32;

        short8 ah[4], bh[4], al[4], bl[4];
#pragma unroll
        for (int i = 0; i < 4; i++) {
            ah[i] = *(const short8*)&ash[(wm + i * 16 + l16) * 32 + quad * 8];
            bh[i] = *(const short8*)&bsh[(wn + i * 16 + l16) * 32 + quad * 8];
            if constexpr (NTERMS == 3) {
                al[i] = *(const short8*)&asl[(wm + i * 16 + l16) * 32 + quad * 8];
                bl[i] = *(const short8*)&bsl[(wn + i * 16 + l16) * 32 + quad * 8];
            }
        }
#pragma unroll
        for (int i = 0; i < 4; i++)
#pragma unroll
            for (int j = 0; j < 4; j++) {
                acc[i][j] = __builtin_amdgcn_mfma_f32_16x16x32_bf16(ah[i], bh[j], acc[i][j], 0, 0, 0);
                if constexpr (NTERMS == 3) {
                    acc[i][j] = __builtin_amdgcn_mfma_f32_16x16x32_bf16(ah[i], bl[j], acc[i][j], 0, 0, 0);
                    acc[i][j] = __builtin_amdgcn_mfma_f32_16x16x32_bf16(al[i], bh[j], acc[i][j], 0, 0, 0);
                }
            }
        cur ^= 1;
    }

    // --- softmax partial stats (per row of this block's 128-col n-tile) ----
    if constexpr (STATS) {
        float* sred = (float*)(smem + 2 * SET);   // 128 rows x 2 wave-halves
        float mrow[4][4], lrow[4][4];
#pragma unroll
        for (int i = 0; i < 4; i++)
#pragma unroll
            for (int r = 0; r < 4; r++) {
                float m = acc[i][0][r];
#pragma unroll
                for (int j = 1; j < 4; j++) m = fmaxf(m, acc[i][j][r]);
                m = fmaxf(m, __shfl_xor(m, 1));
                m = fmaxf(m, __shfl_xor(m, 2));
                m = fmaxf(m, __shfl_xor(m, 4));
                m = fmaxf(m, __shfl_xor(m, 8));
                mrow[i][r] = m;
            }
        __syncthreads();
        if (l16 == 0) {
#pragma unroll
            for (int i = 0; i < 4; i++)
#pragma unroll
                for (int r = 0; r < 4; r++)
                    sred[(wm + i * 16 + quad * 4 + r) * 2 + (wave & 1)] = mrow[i][r];
        }
        __syncthreads();
#pragma unroll
        for (int i = 0; i < 4; i++)
#pragma unroll
            for (int r = 0; r < 4; r++) {
                int row = wm + i * 16 + quad * 4 + r;
                mrow[i][r] = fmaxf(sred[row * 2], sred[row * 2 + 1]);
            }
        __syncthreads();   // everyone done reading maxes before l overwrites
#pragma unroll
        for (int i = 0; i < 4; i++)
#pragma unroll
            for (int r = 0; r < 4; r++) {
                float s = 0.f;
#pragma unroll
                for (int j = 0; j < 4; j++) s += __expf(acc[i][j][r] - mrow[i][r]);
                s += __shfl_xor(s, 1);
                s += __shfl_xor(s, 2);
                s += __shfl_xor(s, 4);
                s += __shfl_xor(s, 8);
                lrow[i][r] = s;
            }
        if (l16 == 0) {
#pragma unroll
            for (int i = 0; i < 4; i++)
#pragma unroll
                for (int r = 0; r < 4; r++)
                    sred[(wm + i * 16 + quad * 4 + r) * 2 + (wave & 1)] = lrow[i][r];
        }
        __syncthreads();
        if ((wave & 1) == 0 && l16 == 0) {
#pragma unroll
            for (int i = 0; i < 4; i++)
#pragma unroll
                for (int r = 0; r < 4; r++) {
                    int row = wm + i * 16 + quad * 4 + r;
                    long grow = tile_m + row;
                    float2 v; v.x = mrow[i][r];
                    v.y = sred[row * 2] + sred[row * 2 + 1];
                    stats[((long)bz * 2048 + grow) * 16 + blockIdx.x] = v;
                }
        }
    }

    // epilogue: D row = quad*4 + reg, col = lane&15  (m89-verified mapping)
#pragma unroll
    for (int i = 0; i < 4; i++)
#pragma unroll
        for (int j = 0; j < 4; j++) {
            const long row0 = tile_m + wm + i * 16 + quad * 4;
            const long col  = tile_n + wn + j * 16 + l16;
#pragma unroll
            for (int r = 0; r < 4; r++) {
                float v = acc[i][j][r];
                if constexpr (SPLIT_OUT) {
                    long idx = (long)bz * sC + (row0 + r) * (long)ldc + col;
                    short h = f2bf(v);
                    Ch[idx] = h;
                    Cl[idx] = f2bf(v - bf2f(h));
                } else {
                    C[(long)bz * sC + (row0 + r) * (long)ldc + col] = v;
                }
            }
        }
}

// ---------------------------------------------------------------------------
// combine: per row, fold 16 tile partials -> (max, 1/sum)
// ---------------------------------------------------------------------------
__global__ __launch_bounds__(256)
void combine_kernel(const float2* __restrict__ stats, float* __restrict__ Mrow,
                    float* __restrict__ Linv)
{
    long r = (long)blockIdx.x * 256 + threadIdx.x;   // 0..16383
    const float2* s = stats + r * 16;
    float2 v[16];
#pragma unroll
    for (int i = 0; i < 16; i++) v[i] = s[i];
    float m = v[0].x;
#pragma unroll
    for (int i = 1; i < 16; i++) m = fmaxf(m, v[i].x);
    float l = 0.f;
#pragma unroll
    for (int i = 0; i < 16; i++) l += v[i].y * __expf(v[i].x - m);
    Mrow[r] = m;
    Linv[r] = 1.f / l;
}

// ---------------------------------------------------------------------------
// pv_fused: Out[b][q][e] = (1/l_q) * sum_s exp(S[b][q][s] - m_q) * enc[b][s][e]
// M=128 q, N=128 e (grid.x=4 slices), K=2048 s, BK=32.
// A staged through registers: load S fp32 -> exp -> bf16 -> ds_write (dbuf,
// loads issued right after the barrier so vmcnt wait overlaps the MFMAs).
// B = enc_t via global_load_lds.  1/l applied in epilogue.
// LDS layout (shorts): A0 @0, A1 @4096, B0 @8192, B1 @12288  (32 KB total).
// ---------------------------------------------------------------------------
__global__ __launch_bounds__(256, 2)
void pv_fused(const float* __restrict__ S, const short* __restrict__ encT,
              const float* __restrict__ Mrow, const float* __restrict__ Linv,
              float* __restrict__ Out)
{
    extern __shared__ char smem_raw[];
    short* smem = (short*)smem_raw;
    constexpr int ABUF = 128 * 32;          // 4096 shorts per buffer

    const int tid  = threadIdx.x;
    const int wave = tid >> 6;
    const int lane = tid & 63;
    const int quad = lane >> 4;
    const int l16  = lane & 15;
    const int wm   = (wave >> 1) * 64;
    const int wn   = (wave & 1) * 64;

    const int  bz     = blockIdx.z;
    const long tile_m = (long)blockIdx.y * 128;   // q rows
    const long tile_n = (long)blockIdx.x * 128;   // e cols

    // A staging: thread t -> q-row t>>1, s-half (t&1)*16 (64B contig fp32)
    const int arow = tid >> 1;
    const int ascol = (tid & 1) * 16;
    const float* pS = S + ((long)bz * 2048 + tile_m + arow) * 2048 + ascol;
    const int aw_off = arow * 32 + ascol;
    const float m_r = Mrow[bz * 2048 + tile_m + arow];

    // B staging (same pattern as gemm_bt)
    const short* pB = encT + (long)bz * 512 * 2048 + (tile_n + (tid >> 2)) * 2048 + (tid & 3) * 8;
    const int b_lds = (tid >> 2) * 32 + (tid & 3) * 8;

    f32x4 acc[4][4] = {};
    float a_pre[16];

    // prologue: tile 0
#pragma unroll
    for (int c = 0; c < 4; c++) *(f32x4*)&a_pre[c * 4] = *(const f32x4*)(pS + c * 4);
    gload_lds16(pB,             smem + 2 * ABUF + b_lds);
    gload_lds16(pB + 64 * 2048, smem + 2 * ABUF + b_lds + 64 * 32);
    {
        short8 h0, h1;
#pragma unroll
        for (int e = 0; e < 8; e++) h0[e] = f2bf(__expf(a_pre[e] - m_r));
#pragma unroll
        for (int e = 0; e < 8; e++) h1[e] = f2bf(__expf(a_pre[8 + e] - m_r));
        *(short8*)(smem + aw_off)     = h0;
        *(short8*)(smem + aw_off + 8) = h1;
    }
    int cur = 0;

    for (int k0 = 0; k0 < 2048; k0 += 32) {
        __syncthreads();            // staging(cur) complete (vmcnt + lgkm)
        const bool more = (k0 + 32 < 2048);
        if (more) {
            const float* ps = pS + k0 + 32;
#pragma unroll
            for (int c = 0; c < 4; c++) *(f32x4*)&a_pre[c * 4] = *(const f32x4*)(ps + c * 4);
            gload_lds16(pB + k0 + 32,             smem + (2 + (cur ^ 1)) * ABUF + b_lds);
            gload_lds16(pB + 64 * 2048 + k0 + 32, smem + (2 + (cur ^ 1)) * ABUF + b_lds + 64 * 32);
        }

        short* Ac = smem + cur * ABUF;
        short* Bc = smem + (2 + cur) * ABUF;
        short8 a[4], b[4];
#pragma unroll
        for (int i = 0; i < 4; i++) {
            a[i] = *(const short8*)&Ac[(wm + i * 16 + l16) * 32 + quad * 8];
            b[i] = *(const short8*)&Bc[(wn + i * 16 + l16) * 32 + quad * 8];
        }
#pragma unroll
        for (int i = 0; i < 4; i++)
#pragma unroll
            for (int j = 0; j < 4; j++)
                acc[i][j] = __builtin_amdgcn_mfma_f32_16x16x32_bf16(a[i], b[j], acc[i][j], 0, 0, 0);

        if (more) {   // transform after MFMAs: vmcnt wait overlapped compute
            short8 h0, h1;
#pragma unroll
            for (int e = 0; e < 8; e++) h0[e] = f2bf(__expf(a_pre[e] - m_r));
#pragma unroll
            for (int e = 0; e < 8; e++) h1[e] = f2bf(__expf(a_pre[8 + e] - m_r));
            short* An = smem + (cur ^ 1) * ABUF;
            *(short8*)(An + aw_off)     = h0;
            *(short8*)(An + aw_off + 8) = h1;
        }
        cur ^= 1;
    }

    // epilogue: scale rows by 1/l, store fp32
    float li[4][4];
#pragma unroll
    for (int i = 0; i < 4; i++)
#pragma unroll
        for (int r = 0; r < 4; r++)
            li[i][r] = Linv[bz * 2048 + tile_m + wm + i * 16 + quad * 4 + r];
#pragma unroll
    for (int i = 0; i < 4; i++)
#pragma unroll
        for (int j = 0; j < 4; j++) {
            const long row0 = tile_m + wm + i * 16 + quad * 4;
            const long col  = tile_n + wn + j * 16 + l16;
#pragma unroll
            for (int r = 0; r < 4; r++)
                Out[((long)bz * 2048 + row0 + r) * 512 + col] = acc[i][j][r] * li[i][r];
        }
}

// ---------------------------------------------------------------------------
extern "C" void kernel_launch(void* const* d_in, const int* in_sizes, int n_in,
                              void* d_out, int out_size, void* d_ws, size_t ws_size,
                              hipStream_t stream)
{
    const float* enc = (const float*)d_in[0];   // [8,2048,512]
    const float* dec = (const float*)d_in[1];   // [8,2048,512]
    const float* W   = (const float*)d_in[2];   // [512,512]
    float* out = (float*)d_out;                 // [8,2048,512]

    const long BSE = 8l * 2048 * 512;           // 8388608
    const long NW  = 512l * 512;

    char* p = (char*)d_ws;
    auto take = [&](long bytes) { char* r = p; p += (bytes + 255) & ~255l; return r; };
    short* enc_hi = (short*)take(BSE * 2);
    short* enc_lo = (short*)take(BSE * 2);
    short* dec_hi = (short*)take(BSE * 2);
    short* dec_lo = (short*)take(BSE * 2);
    short* ep_hi  = (short*)take(BSE * 2);
    short* ep_lo  = (short*)take(BSE * 2);
    short* enc_t  = (short*)take(BSE * 2);
    short* wt_hi  = (short*)take(NW * 2);
    short* wt_lo  = (short*)take(NW * 2);
    float* logits = (float*)take(8l * 2048 * 2048 * 4);   // 134 MB
    // stats (2 MB) + Mrow/Linv (64 KB each) alias enc_lo: enc_lo is dead
    // after enc_proj; stats are written by the (later) logits gemm.
    float2* stats = (float2*)enc_lo;
    float*  MrowA = (float*)(enc_lo + 4l * 1024 * 1024);
    float*  LinvA = (float*)(enc_lo + 5l * 1024 * 1024);
    (void)ws_size; (void)in_sizes; (void)n_in; (void)out_size;

    split_kernel<<<4096, 256, 0, stream>>>(enc, enc_hi, enc_lo);
    split_kernel<<<4096, 256, 0, stream>>>(dec, dec_hi, dec_lo);
    split_w_kernel<<<1024, 256, 0, stream>>>(W, wt_hi, wt_lo);
    transpose_bf16_kernel<<<dim3(64, 16, 8), 256, 0, stream>>>(enc_hi, enc_t);

    // enc_proj = enc @ W  (M=16384, N=512, K=512), 3-term, split bf16 output
    gemm_bt<3, true, false><<<dim3(4, 128, 1), 256, 64 * 1024, stream>>>(
        enc_hi, enc_lo, wt_hi, wt_lo, nullptr, ep_hi, ep_lo, nullptr,
        512, 512, 512, 512, 0, 0, 0);

    // logits[b] = dec[b] @ ep[b]^T  (M=2048, N=2048, K=512) x 8, 3-term,
    // + per-(row, n-tile) softmax partials
    gemm_bt<3, false, true><<<dim3(16, 16, 8), 256, 64 * 1024 + 1024, stream>>>(
        dec_hi, dec_lo, ep_hi, ep_lo, logits, nullptr, nullptr, stats,
        512, 512, 512, 2048, 2048l * 512, 2048l * 512, 2048l * 2048);

    combine_kernel<<<64, 256, 0, stream>>>(stats, MrowA, LinvA);

    // out[b] = softmax(S[b]) @ enc[b]  (fused exp; M=2048, N=512, K=2048) x 8
    pv_fused<<<dim3(4, 16, 8), 256, 32 * 1024, stream>>>(
        logits, enc_t, MrowA, LinvA, out);
}

// Round 5
// 370.159 us; speedup vs baseline: 1.1341x; 1.1341x over previous
//
#include <hip/hip_runtime.h>
#include <cstdint>

// ---------------------------------------------------------------------------
// Attention (Luong general): out = softmax(dec @ (enc@W)^T) @ enc
// B=8, S_enc=S_dec=2048, H=512, fp32 in/out.
//
// bf16 MFMA; split-precision (hi+lo bf16, 3-term) for the matmuls feeding
// softmax (logit std ~512, top-2 gap ~131: plain bf16 would flip argmaxes).
// Round 5: PV rewritten as pv_wide -- one block = 64 q-rows x FULL 512 e
// (8 waves of 64x64), grid 32x8 = 256 blocks = 1/CU.  S fp32 read exactly
// once (round 4's grid.x=4 re-read S 4x -> 280 MB FETCH, memory-bound).
// B (enc_t, L2-resident 2 MB/batch) loaded straight into register fragments
// (no LDS), prefetched 1 iter ahead; S register-prefetched 2 iters ahead of
// its exp->bf16->LDS transform.
// ---------------------------------------------------------------------------

#define DEVINL __device__ __forceinline__

typedef __attribute__((ext_vector_type(8))) short short8;
typedef __attribute__((ext_vector_type(4))) short short4v;
typedef __attribute__((ext_vector_type(4))) float f32x4;

DEVINL short f2bf(float x) {
    union { float f; uint32_t u; } v; v.f = x;
    uint32_t r = v.u + 0x7FFFu + ((v.u >> 16) & 1u);   // RNE
    return (short)(r >> 16);
}
DEVINL float bf2f(short h) {
    union { uint32_t u; float f; } v; v.u = ((uint32_t)(uint16_t)h) << 16;
    return v.f;
}

DEVINL void gload_lds16(const void* g, void* l) {
    __builtin_amdgcn_global_load_lds(
        (const __attribute__((address_space(1))) char*)g,
        (__attribute__((address_space(3))) char*)l, 16, 0, 0);
}

// ---------------------------------------------------------------------------
// split fp32 -> (hi, lo) bf16 arrays.  8 elems/thread, exact-cover grids.
// ---------------------------------------------------------------------------
__global__ __launch_bounds__(256)
void split_kernel(const float* __restrict__ x, short* __restrict__ hi,
                  short* __restrict__ lo)
{
    long i = ((long)blockIdx.x * 256 + threadIdx.x) * 8;
    f32x4 a = *(const f32x4*)(x + i);
    f32x4 b = *(const f32x4*)(x + i + 4);
    short8 h, l;
#pragma unroll
    for (int j = 0; j < 4; j++) {
        short ha = f2bf(a[j]); h[j] = ha;     l[j] = f2bf(a[j] - bf2f(ha));
        short hb = f2bf(b[j]); h[4 + j] = hb; l[4 + j] = f2bf(b[j] - bf2f(hb));
    }
    *(short8*)(hi + i) = h;
    *(short8*)(lo + i) = l;
}

// W[512k][512n] -> Wt_hi/lo[n][k]
__global__ __launch_bounds__(256)
void split_w_kernel(const float* __restrict__ w, short* __restrict__ wth,
                    short* __restrict__ wtl)
{
    int idx = blockIdx.x * 256 + threadIdx.x;   // k*512 + n
    int k = idx >> 9, n = idx & 511;
    float v = w[idx];
    short h = f2bf(v);
    wth[(long)n * 512 + k] = h;
    wtl[(long)n * 512 + k] = f2bf(v - bf2f(h));
}

// enc_hi[b][s][e] bf16 -> enc_t[b][e][s] bf16 (PV B-operand)
__global__ __launch_bounds__(256)
void transpose_bf16_kernel(const short* __restrict__ x, short* __restrict__ xt)
{
    __shared__ short tile[32][33];
    const int b  = blockIdx.z;
    const int s0 = blockIdx.x * 32;
    const int e0 = blockIdx.y * 32;
    const short* px = x + (long)b * 2048 * 512;
    short* pt = xt + (long)b * 512 * 2048;
    const int tx = threadIdx.x & 31;
    const int ty = threadIdx.x >> 5;   // 0..7
#pragma unroll
    for (int r = 0; r < 32; r += 8)
        tile[ty + r][tx] = px[(long)(s0 + ty + r) * 512 + e0 + tx];
    __syncthreads();
#pragma unroll
    for (int r = 0; r < 32; r += 8)
        pt[(long)(e0 + ty + r) * 2048 + s0 + tx] = tile[tx][ty + r];
}

// ---------------------------------------------------------------------------
// gemm_bt: C[m][n] = sum_k A[m][k]*B[n][k]  (both operands K-contiguous).
// 128x128 tile, BK=32, 4 waves (2x2 of 64x64), 16x16x32 bf16 MFMA,
// double-buffered LDS staging (one barrier/iter; prefetch before consume).
// NTERMS=3: acc += Ah*Bh + Ah*Bl + Al*Bh.
// SPLIT_OUT: write hi/lo bf16 pair (for enc_proj).
// STATS: epilogue also writes per-(row, n-tile) softmax partials
//   stats[(b*2048+row)*16 + blockIdx.x] = (m_p, sum_j exp(x - m_p)).
// ---------------------------------------------------------------------------
template<int NTERMS, bool SPLIT_OUT, bool STATS>
__global__ __launch_bounds__(256, 2)
void gemm_bt(const short* __restrict__ Ah, const short* __restrict__ Al,
             const short* __restrict__ Bh, const short* __restrict__ Bl,
             float* __restrict__ C, short* __restrict__ Ch, short* __restrict__ Cl,
             float2* __restrict__ stats,
             int K, int lda, int ldb, int ldc,
             long sA, long sB, long sC)
{
    extern __shared__ char smem_raw[];
    constexpr int OPS = (NTERMS == 3) ? 4 : 2;     // operand planes per set
    constexpr int SET = 128 * 32 * OPS;            // shorts per buffer set
    short* smem = (short*)smem_raw;                // 2 sets (+1KB stats)

    const int tid  = threadIdx.x;
    const int wave = tid >> 6;
    const int lane = tid & 63;
    const int quad = lane >> 4;
    const int l16  = lane & 15;
    const int wm   = (wave >> 1) * 64;
    const int wn   = (wave & 1) * 64;

    const long tile_m = (long)blockIdx.y * 128;
    const long tile_n = (long)blockIdx.x * 128;
    const int  bz     = blockIdx.z;

    const short* pAh = Ah + (long)bz * sA;
    const short* pBh = Bh + (long)bz * sB;
    const short* pAl = (NTERMS == 3) ? (Al + (long)bz * sA) : nullptr;
    const short* pBl = (NTERMS == 3) ? (Bl + (long)bz * sB) : nullptr;

    // staging: thread t -> row t>>2, k-subchunk (t&3)*8; LDS byte off = 16*t
    const int srow = tid >> 2;
    const int skq  = (tid & 3) * 8;
    const int lds_off = srow * 32 + skq;
    const long ga0 = (tile_m + srow) * (long)lda + skq;
    const long gb0 = (tile_n + srow) * (long)ldb + skq;

    auto stage = [&](int k0, int buf) {
        short* s   = smem + buf * SET;
        short* ash = s;
        short* bsh = s + 128 * 32;
        gload_lds16(pAh + ga0 + k0,             ash + lds_off);
        gload_lds16(pAh + ga0 + 64l * lda + k0, ash + lds_off + 64 * 32);
        gload_lds16(pBh + gb0 + k0,             bsh + lds_off);
        gload_lds16(pBh + gb0 + 64l * ldb + k0, bsh + lds_off + 64 * 32);
        if constexpr (NTERMS == 3) {
            short* asl = s + 2 * 128 * 32;
            short* bsl = s + 3 * 128 * 32;
            gload_lds16(pAl + ga0 + k0,             asl + lds_off);
            gload_lds16(pAl + ga0 + 64l * lda + k0, asl + lds_off + 64 * 32);
            gload_lds16(pBl + gb0 + k0,             bsl + lds_off);
            gload_lds16(pBl + gb0 + 64l * ldb + k0, bsl + lds_off + 64 * 32);
        }
    };

    f32x4 acc[4][4] = {};
    stage(0, 0);
    int cur = 0;

    for (int k0 = 0; k0 < K; k0 += 32) {
        __syncthreads();                    // drains vmcnt: stage(cur) done
        if (k0 + 32 < K) stage(k0 + 32, cur ^ 1);   // prefetch next tile

        short* s   = smem + cur * SET;
        short* ash = s;
        short* bsh = s + 128 * 32;
        short* asl = s + 2 * 128 * 32;
        short* bsl = s + 3 * 128 * 32;

        short8 ah[4], bh[4], al[4], bl[4];
#pragma unroll
        for (int i = 0; i < 4; i++) {
            ah[i] = *(const short8*)&ash[(wm + i * 16 + l16) * 32 + quad * 8];
            bh[i] = *(const short8*)&bsh[(wn + i * 16 + l16) * 32 + quad * 8];
            if constexpr (NTERMS == 3) {
                al[i] = *(const short8*)&asl[(wm + i * 16 + l16) * 32 + quad * 8];
                bl[i] = *(const short8*)&bsl[(wn + i * 16 + l16) * 32 + quad * 8];
            }
        }
#pragma unroll
        for (int i = 0; i < 4; i++)
#pragma unroll
            for (int j = 0; j < 4; j++) {
                acc[i][j] = __builtin_amdgcn_mfma_f32_16x16x32_bf16(ah[i], bh[j], acc[i][j], 0, 0, 0);
                if constexpr (NTERMS == 3) {
                    acc[i][j] = __builtin_amdgcn_mfma_f32_16x16x32_bf16(ah[i], bl[j], acc[i][j], 0, 0, 0);
                    acc[i][j] = __builtin_amdgcn_mfma_f32_16x16x32_bf16(al[i], bh[j], acc[i][j], 0, 0, 0);
                }
            }
        cur ^= 1;
    }

    // --- softmax partial stats (per row of this block's 128-col n-tile) ----
    if constexpr (STATS) {
        float* sred = (float*)(smem + 2 * SET);   // 128 rows x 2 wave-halves
        float mrow[4][4], lrow[4][4];
#pragma unroll
        for (int i = 0; i < 4; i++)
#pragma unroll
            for (int r = 0; r < 4; r++) {
                float m = acc[i][0][r];
#pragma unroll
                for (int j = 1; j < 4; j++) m = fmaxf(m, acc[i][j][r]);
                m = fmaxf(m, __shfl_xor(m, 1));
                m = fmaxf(m, __shfl_xor(m, 2));
                m = fmaxf(m, __shfl_xor(m, 4));
                m = fmaxf(m, __shfl_xor(m, 8));
                mrow[i][r] = m;
            }
        __syncthreads();
        if (l16 == 0) {
#pragma unroll
            for (int i = 0; i < 4; i++)
#pragma unroll
                for (int r = 0; r < 4; r++)
                    sred[(wm + i * 16 + quad * 4 + r) * 2 + (wave & 1)] = mrow[i][r];
        }
        __syncthreads();
#pragma unroll
        for (int i = 0; i < 4; i++)
#pragma unroll
            for (int r = 0; r < 4; r++) {
                int row = wm + i * 16 + quad * 4 + r;
                mrow[i][r] = fmaxf(sred[row * 2], sred[row * 2 + 1]);
            }
        __syncthreads();   // everyone done reading maxes before l overwrites
#pragma unroll
        for (int i = 0; i < 4; i++)
#pragma unroll
            for (int r = 0; r < 4; r++) {
                float s = 0.f;
#pragma unroll
                for (int j = 0; j < 4; j++) s += __expf(acc[i][j][r] - mrow[i][r]);
                s += __shfl_xor(s, 1);
                s += __shfl_xor(s, 2);
                s += __shfl_xor(s, 4);
                s += __shfl_xor(s, 8);
                lrow[i][r] = s;
            }
        if (l16 == 0) {
#pragma unroll
            for (int i = 0; i < 4; i++)
#pragma unroll
                for (int r = 0; r < 4; r++)
                    sred[(wm + i * 16 + quad * 4 + r) * 2 + (wave & 1)] = lrow[i][r];
        }
        __syncthreads();
        if ((wave & 1) == 0 && l16 == 0) {
#pragma unroll
            for (int i = 0; i < 4; i++)
#pragma unroll
                for (int r = 0; r < 4; r++) {
                    int row = wm + i * 16 + quad * 4 + r;
                    long grow = tile_m + row;
                    float2 v; v.x = mrow[i][r];
                    v.y = sred[row * 2] + sred[row * 2 + 1];
                    stats[((long)bz * 2048 + grow) * 16 + blockIdx.x] = v;
                }
        }
    }

    // epilogue: D row = quad*4 + reg, col = lane&15  (m89-verified mapping)
#pragma unroll
    for (int i = 0; i < 4; i++)
#pragma unroll
        for (int j = 0; j < 4; j++) {
            const long row0 = tile_m + wm + i * 16 + quad * 4;
            const long col  = tile_n + wn + j * 16 + l16;
#pragma unroll
            for (int r = 0; r < 4; r++) {
                float v = acc[i][j][r];
                if constexpr (SPLIT_OUT) {
                    long idx = (long)bz * sC + (row0 + r) * (long)ldc + col;
                    short h = f2bf(v);
                    Ch[idx] = h;
                    Cl[idx] = f2bf(v - bf2f(h));
                } else {
                    C[(long)bz * sC + (row0 + r) * (long)ldc + col] = v;
                }
            }
        }
}

// ---------------------------------------------------------------------------
// combine: per row, fold 16 tile partials -> (max, 1/sum)
// ---------------------------------------------------------------------------
__global__ __launch_bounds__(256)
void combine_kernel(const float2* __restrict__ stats, float* __restrict__ Mrow,
                    float* __restrict__ Linv)
{
    long r = (long)blockIdx.x * 256 + threadIdx.x;   // 0..16383
    const float2* s = stats + r * 16;
    float2 v[16];
#pragma unroll
    for (int i = 0; i < 16; i++) v[i] = s[i];
    float m = v[0].x;
#pragma unroll
    for (int i = 1; i < 16; i++) m = fmaxf(m, v[i].x);
    float l = 0.f;
#pragma unroll
    for (int i = 0; i < 16; i++) l += v[i].y * __expf(v[i].x - m);
    Mrow[r] = m;
    Linv[r] = 1.f / l;
}

// ---------------------------------------------------------------------------
// pv_wide: Out[b][q][e] = (1/l_q) * sum_s exp(S[b][q][s] - m_q) * enc[b][s][e]
// Block tile: 64 q x 512 e (FULL e width -> S read exactly once).
// 512 threads = 8 waves, wave w -> e-range [w*64, w*64+64); per-wave acc
// 4x4 f32x4 (64 VGPRs).  Grid (32 q-tiles, 8 batches) = 256 blocks = 1/CU.
// A: S fp32 chunk (4 elems/thread) reg-prefetched at distance 2 ->
//    exp(s-m) -> bf16 -> LDS (dbuf 2x4KB).
// B: enc_t fragments loaded straight from global (L2-resident 2 MB/batch)
//    into registers, prefetched 1 iter ahead.  No B LDS.
// ---------------------------------------------------------------------------
__global__ __launch_bounds__(512, 2)
void pv_wide(const float* __restrict__ S, const short* __restrict__ encT,
             const float* __restrict__ Mrow, const float* __restrict__ Linv,
             float* __restrict__ Out)
{
    extern __shared__ char smem_raw[];
    short* As = (short*)smem_raw;           // 2 x 64x32 shorts = 8 KB

    const int tid  = threadIdx.x;
    const int wave = tid >> 6;              // 0..7 -> e-slice
    const int lane = tid & 63;
    const int quad = lane >> 4;
    const int l16  = lane & 15;

    const int  bz     = blockIdx.y;
    const long tile_m = (long)blockIdx.x * 64;    // q rows

    // A staging: thread t -> q-row t>>3, cols (t&7)*4  (16 B/thread)
    const int arow  = tid >> 3;
    const int acol  = (tid & 7) * 4;
    const float* pS = S + ((long)bz * 2048 + tile_m + arow) * 2048 + acol;
    const int aoff  = arow * 32 + acol;
    const float m_r = Mrow[bz * 2048 + tile_m + arow];

    // B fragments: row = wave*64 + j*16 + l16 of enc_t[bz], col window quad*8
    const short* pB = encT + (long)bz * 512 * 2048
                    + (long)(wave * 64 + l16) * 2048 + quad * 8;

    f32x4 acc[4][4] = {};
    short8 bfr[2][4];
    f32x4 sp[2];

    // prologue: A(0) staged directly; sp[1] = S(32); bfr[0] = B(0)
    {
        f32x4 s0 = *(const f32x4*)pS;
        short4v h;
#pragma unroll
        for (int e = 0; e < 4; e++) h[e] = f2bf(__expf(s0[e] - m_r));
        *(short4v*)(As + aoff) = h;
    }
    sp[1] = *(const f32x4*)(pS + 32);
#pragma unroll
    for (int j = 0; j < 4; j++)
        bfr[0][j] = *(const short8*)(pB + (long)j * 16 * 2048);

    auto step = [&](int k0, int p) {
        __syncthreads();                    // A(k0) in LDS buf p
        const bool more  = (k0 + 32 < 2048);
        const bool more2 = (k0 + 64 < 2048);
        if (more2) sp[p] = *(const f32x4*)(pS + k0 + 64);   // distance 2
        if (more) {
#pragma unroll
            for (int j = 0; j < 4; j++)
                bfr[p ^ 1][j] = *(const short8*)(pB + (long)j * 16 * 2048 + k0 + 32);
        }
        short8 a[4];
#pragma unroll
        for (int i = 0; i < 4; i++)
            a[i] = *(const short8*)&As[p * 2048 + (i * 16 + l16) * 32 + quad * 8];
#pragma unroll
        for (int i = 0; i < 4; i++)
#pragma unroll
            for (int j = 0; j < 4; j++)
                acc[i][j] = __builtin_amdgcn_mfma_f32_16x16x32_bf16(a[i], bfr[p][j], acc[i][j], 0, 0, 0);
        if (more) {                         // transform S(k0+32) (= sp[p^1])
            f32x4 sv = sp[p ^ 1];
            short4v h;
#pragma unroll
            for (int e = 0; e < 4; e++) h[e] = f2bf(__expf(sv[e] - m_r));
            *(short4v*)(As + (p ^ 1) * 2048 + aoff) = h;
        }
    };

    for (int k0 = 0; k0 < 2048; k0 += 64) {
        step(k0, 0);
        step(k0 + 32, 1);
    }

    // epilogue: scale rows by 1/l, store fp32
    float li[4][4];
#pragma unroll
    for (int i = 0; i < 4; i++)
#pragma unroll
        for (int r = 0; r < 4; r++)
            li[i][r] = Linv[bz * 2048 + tile_m + i * 16 + quad * 4 + r];
#pragma unroll
    for (int i = 0; i < 4; i++)
#pragma unroll
        for (int j = 0; j < 4; j++) {
            const long row0 = tile_m + i * 16 + quad * 4;
            const long col  = wave * 64 + j * 16 + l16;
#pragma unroll
            for (int r = 0; r < 4; r++)
                Out[((long)bz * 2048 + row0 + r) * 512 + col] = acc[i][j][r] * li[i][r];
        }
}

// ---------------------------------------------------------------------------
extern "C" void kernel_launch(void* const* d_in, const int* in_sizes, int n_in,
                              void* d_out, int out_size, void* d_ws, size_t ws_size,
                              hipStream_t stream)
{
    const float* enc = (const float*)d_in[0];   // [8,2048,512]
    const float* dec = (const float*)d_in[1];   // [8,2048,512]
    const float* W   = (const float*)d_in[2];   // [512,512]
    float* out = (float*)d_out;                 // [8,2048,512]

    const long BSE = 8l * 2048 * 512;           // 8388608
    const long NW  = 512l * 512;

    char* p = (char*)d_ws;
    auto take = [&](long bytes) { char* r = p; p += (bytes + 255) & ~255l; return r; };
    short* enc_hi = (short*)take(BSE * 2);
    short* enc_lo = (short*)take(BSE * 2);
    short* dec_hi = (short*)take(BSE * 2);
    short* dec_lo = (short*)take(BSE * 2);
    short* ep_hi  = (short*)take(BSE * 2);
    short* ep_lo  = (short*)take(BSE * 2);
    short* enc_t  = (short*)take(BSE * 2);
    short* wt_hi  = (short*)take(NW * 2);
    short* wt_lo  = (short*)take(NW * 2);
    float* logits = (float*)take(8l * 2048 * 2048 * 4);   // 134 MB
    // stats (2 MB) + Mrow/Linv (64 KB each) alias enc_lo: enc_lo is dead
    // after enc_proj; stats are written by the (later) logits gemm.
    float2* stats = (float2*)enc_lo;
    float*  MrowA = (float*)(enc_lo + 4l * 1024 * 1024);
    float*  LinvA = (float*)(enc_lo + 5l * 1024 * 1024);
    (void)ws_size; (void)in_sizes; (void)n_in; (void)out_size;

    split_kernel<<<4096, 256, 0, stream>>>(enc, enc_hi, enc_lo);
    split_kernel<<<4096, 256, 0, stream>>>(dec, dec_hi, dec_lo);
    split_w_kernel<<<1024, 256, 0, stream>>>(W, wt_hi, wt_lo);
    transpose_bf16_kernel<<<dim3(64, 16, 8), 256, 0, stream>>>(enc_hi, enc_t);

    // enc_proj = enc @ W  (M=16384, N=512, K=512), 3-term, split bf16 output
    gemm_bt<3, true, false><<<dim3(4, 128, 1), 256, 64 * 1024, stream>>>(
        enc_hi, enc_lo, wt_hi, wt_lo, nullptr, ep_hi, ep_lo, nullptr,
        512, 512, 512, 512, 0, 0, 0);

    // logits[b] = dec[b] @ ep[b]^T  (M=2048, N=2048, K=512) x 8, 3-term,
    // + per-(row, n-tile) softmax partials
    gemm_bt<3, false, true><<<dim3(16, 16, 8), 256, 64 * 1024 + 1024, stream>>>(
        dec_hi, dec_lo, ep_hi, ep_lo, logits, nullptr, nullptr, stats,
        512, 512, 512, 2048, 2048l * 512, 2048l * 512, 2048l * 2048);

    combine_kernel<<<64, 256, 0, stream>>>(stats, MrowA, LinvA);

    // out[b] = softmax(S[b]) @ enc[b]  (fused exp; 64q x 512e blocks) x 8
    pv_wide<<<dim3(32, 8), 512, 8 * 1024, stream>>>(
        logits, enc_t, MrowA, LinvA, out);
}